// Round 14
// baseline (562.166 us; speedup 1.0000x reference)
//
#include <hip/hip_runtime.h>
#include <cstdint>

#define B_ 2
#define S_ 4096
#define H_ 2048
#define NH_ 16
#define HD_ 128
#define BLOCK_ 256
#define NC_ (S_/BLOCK_)   // 16
#define M_ (B_*S_)        // 8192
#define EPS_ 1e-5f

typedef unsigned short ushort_t;
typedef unsigned short u16x4 __attribute__((ext_vector_type(4)));
typedef short frag_ab __attribute__((ext_vector_type(8)));   // 8 bf16 (4 VGPRs)
typedef float frag_cd __attribute__((ext_vector_type(4)));   // 4 f32

static __device__ inline float bf2f(ushort_t u) {
    union { unsigned int i; float f; } x;
    x.i = ((unsigned int)u) << 16;
    return x.f;
}
static __device__ inline ushort_t f2bf(float f) {
    union { float f; unsigned int i; } x;
    x.f = f;
    unsigned int r = x.i + 0x7fffu + ((x.i >> 16) & 1u);
    return (ushort_t)(r >> 16);
}

// async global->LDS, 16B per lane; LDS dest is wave-uniform base + lane*16
static __device__ __forceinline__ void gload_lds16(const ushort_t* g, ushort_t* l) {
    __builtin_amdgcn_global_load_lds(
        (__attribute__((address_space(1))) void*)(uintptr_t)g,
        (__attribute__((address_space(3))) void*)l,
        16, 0, 0);
}

#define FENCE_ asm volatile("" ::: "memory")
#define VMW8_  asm volatile("s_waitcnt vmcnt(8)" ::: "memory")
#define VMW2_  asm volatile("s_waitcnt vmcnt(2)" ::: "memory")
#define VMW0_  asm volatile("s_waitcnt vmcnt(0)" ::: "memory")

// ---------------------------------------------------------------------------
// Prep: f32 -> bf16 elementwise cast (hidden).
// ---------------------------------------------------------------------------
__global__ __launch_bounds__(256)
void cast_bf16_kernel(const float* __restrict__ in, ushort_t* __restrict__ out)
{
    int i = blockIdx.x * 256 + threadIdx.x;
    float4 v = reinterpret_cast<const float4*>(in)[i];
    u16x4 o = { f2bf(v.x), f2bf(v.y), f2bf(v.z), f2bf(v.w) };
    *reinterpret_cast<u16x4*>(&out[(size_t)i * 4]) = o;
}

// ---------------------------------------------------------------------------
// Prep: W[K][N] f32 -> WT[N][K] bf16 (tiled transpose+cast).
// ---------------------------------------------------------------------------
__global__ __launch_bounds__(256)
void transpose_cast_kernel(const float* __restrict__ W, ushort_t* __restrict__ WT,
                           int K, int N)
{
    __shared__ float t[32][33];
    const int kb = blockIdx.y * 32, nb = blockIdx.x * 32;
    const int tx = threadIdx.x & 31, ty = threadIdx.x >> 5;  // 32 x 8
    #pragma unroll
    for (int i = 0; i < 4; ++i)
        t[ty + i * 8][tx] = W[(size_t)(kb + ty + i * 8) * N + nb + tx];
    __syncthreads();
    #pragma unroll
    for (int i = 0; i < 4; ++i)
        WT[(size_t)(nb + ty + i * 8) * K + kb + tx] = f2bf(t[tx][ty + i * 8]);
}

// ---------------------------------------------------------------------------
// 256x256 MFMA GEMM: round-8 4-cluster schedule, K-loop unrolled 2x with
// STATIC double-buffer names (m201's "2 K-tiles/iter") so every ds_read
// address is lane-constant + compile-time immediate (no runtime cur^=1
// pointer flip -> address calc VALU drops out of the hot loop).
// ---------------------------------------------------------------------------
template<int MODE>
__global__ __launch_bounds__(512, 2)
void gemm256(const ushort_t* __restrict__ A, const ushort_t* __restrict__ BT,
             int M, int N, int K,
             float* __restrict__ Cf,
             ushort_t* __restrict__ qo, ushort_t* __restrict__ ko,
             ushort_t* __restrict__ kTo, ushort_t* __restrict__ vTo,
             ushort_t* __restrict__ gateo, const float* __restrict__ mask)
{
    __shared__ __align__(16) ushort_t LA[2][16384];
    __shared__ __align__(16) ushort_t LB[2][16384];

    const int tid  = threadIdx.x;
    const int lane = tid & 63, wid = tid >> 6;
    const int wm = wid >> 2, wn = wid & 3;
    const int l15 = lane & 15, l4 = lane >> 4;
    const int trow = tid >> 3;
    const int xk   = (tid & 7) ^ (trow & 7);

    const int nwg = gridDim.x;
    const int lin = blockIdx.x;
    const int virt = (lin & 7) * (nwg >> 3) + (lin >> 3);
    const int NBX = N >> 8;
    const int by = virt / NBX, bx = virt - by * NBX;
    const int rowBase = by * 256, colBase = bx * 256;

    frag_cd acc[8][4];
    #pragma unroll
    for (int m = 0; m < 8; ++m)
        #pragma unroll
        for (int n = 0; n < 4; ++n) acc[m][n] = 0.f;

    frag_ab fa[4][2];
    frag_ab fb[2][2][2];

    #define RDF(Lp, row_, sl_) \
        (*reinterpret_cast<const frag_ab*>( \
            reinterpret_cast<const char*>(Lp) + (row_) * 128 + ((((sl_) ^ ((row_) & 7)) & 7) << 4)))
    #define STG(Gp, base_, i_, kt_, Lp) \
        gload_lds16((Gp) + (size_t)((base_) + (i_) * 64 + trow) * K + (kt_) + xk * 8, \
                    (Lp) + (i_) * 4096 + wid * 512)

    const int NT = K >> 6;   // even (K=2048 -> 32)

    // One K-tile body (round-8 schedule: 4 clusters, 2 barriers, counted vmcnt)
    #define KTILE(AbP, BbP, AnP, BnP, TNEXT)                                        \
    do {                                                                            \
        const bool more = (TNEXT) < NT;                                             \
        const int ktn = (TNEXT) << 6;                                               \
        /* C1 */                                                                    \
        _Pragma("unroll")                                                           \
        for (int mi = 0; mi < 4; ++mi)                                              \
            _Pragma("unroll")                                                       \
            for (int ks = 0; ks < 2; ++ks)                                          \
                fa[mi][ks] = RDF(AbP, wm * 128 + mi * 16 + l15, ks * 4 + l4);       \
        _Pragma("unroll")                                                           \
        for (int ni = 0; ni < 2; ++ni)                                              \
            _Pragma("unroll")                                                       \
            for (int ks = 0; ks < 2; ++ks)                                          \
                fb[0][ni][ks] = RDF(BbP, wn * 64 + ni * 16 + l15, ks * 4 + l4);     \
        if (more) { STG(BT, colBase, 0, ktn, BnP); STG(BT, colBase, 1, ktn, BnP); } \
        __builtin_amdgcn_s_setprio(1);                                              \
        _Pragma("unroll")                                                           \
        for (int mi = 0; mi < 4; ++mi)                                              \
            _Pragma("unroll")                                                       \
            for (int ni = 0; ni < 2; ++ni)                                          \
                _Pragma("unroll")                                                   \
                for (int ks = 0; ks < 2; ++ks)                                      \
                    acc[mi][ni] = __builtin_amdgcn_mfma_f32_16x16x32_bf16(          \
                        fa[mi][ks], fb[0][ni][ks], acc[mi][ni], 0, 0, 0);           \
        __builtin_amdgcn_s_setprio(0);                                              \
        /* C2 */                                                                    \
        _Pragma("unroll")                                                           \
        for (int ni = 0; ni < 2; ++ni)                                              \
            _Pragma("unroll")                                                       \
            for (int ks = 0; ks < 2; ++ks)                                          \
                fb[1][ni][ks] = RDF(BbP, wn * 64 + 32 + ni * 16 + l15, ks * 4 + l4);\
        if (more) { STG(BT, colBase, 2, ktn, BnP); STG(BT, colBase, 3, ktn, BnP); } \
        __builtin_amdgcn_s_setprio(1);                                              \
        _Pragma("unroll")                                                           \
        for (int mi = 0; mi < 4; ++mi)                                              \
            _Pragma("unroll")                                                       \
            for (int ni = 0; ni < 2; ++ni)                                          \
                _Pragma("unroll")                                                   \
                for (int ks = 0; ks < 2; ++ks)                                      \
                    acc[mi][2 + ni] = __builtin_amdgcn_mfma_f32_16x16x32_bf16(      \
                        fa[mi][ks], fb[1][ni][ks], acc[mi][2 + ni], 0, 0, 0);       \
        __builtin_amdgcn_s_setprio(0);                                              \
        if (more) { VMW8_; } else { VMW0_; }                                        \
        FENCE_; __builtin_amdgcn_s_barrier();                                       \
        __builtin_amdgcn_sched_barrier(0);                                          \
        /* C3 */                                                                    \
        _Pragma("unroll")                                                           \
        for (int mi = 0; mi < 4; ++mi)                                              \
            _Pragma("unroll")                                                       \
            for (int ks = 0; ks < 2; ++ks)                                          \
                fa[mi][ks] = RDF(AbP, wm * 128 + 64 + mi * 16 + l15, ks * 4 + l4);  \
        if (more) { STG(A, rowBase, 0, ktn, AnP); STG(A, rowBase, 2, ktn, AnP); }   \
        __builtin_amdgcn_s_setprio(1);                                              \
        _Pragma("unroll")                                                           \
        for (int mi = 0; mi < 4; ++mi)                                              \
            _Pragma("unroll")                                                       \
            for (int ni = 0; ni < 2; ++ni)                                          \
                _Pragma("unroll")                                                   \
                for (int ks = 0; ks < 2; ++ks)                                      \
                    acc[4 + mi][ni] = __builtin_amdgcn_mfma_f32_16x16x32_bf16(      \
                        fa[mi][ks], fb[0][ni][ks], acc[4 + mi][ni], 0, 0, 0);       \
        __builtin_amdgcn_s_setprio(0);                                              \
        /* C4 */                                                                    \
        if (more) { STG(A, rowBase, 1, ktn, AnP); STG(A, rowBase, 3, ktn, AnP); }   \
        __builtin_amdgcn_s_setprio(1);                                              \
        _Pragma("unroll")                                                           \
        for (int mi = 0; mi < 4; ++mi)                                              \
            _Pragma("unroll")                                                       \
            for (int ni = 0; ni < 2; ++ni)                                          \
                _Pragma("unroll")                                                   \
                for (int ks = 0; ks < 2; ++ks)                                      \
                    acc[4 + mi][2 + ni] = __builtin_amdgcn_mfma_f32_16x16x32_bf16(  \
                        fa[mi][ks], fb[1][ni][ks], acc[4 + mi][2 + ni], 0, 0, 0);   \
        __builtin_amdgcn_s_setprio(0);                                              \
        if (more) { VMW2_; }                                                        \
        FENCE_; __builtin_amdgcn_s_barrier();                                       \
        __builtin_amdgcn_sched_barrier(0);                                          \
    } while (0)

    // prologue: stage tile 0 in canonical order, drain first 6, barrier
    STG(BT, colBase, 0, 0, &LB[0][0]); STG(BT, colBase, 1, 0, &LB[0][0]);
    STG(BT, colBase, 2, 0, &LB[0][0]); STG(BT, colBase, 3, 0, &LB[0][0]);
    STG(A,  rowBase, 0, 0, &LA[0][0]); STG(A,  rowBase, 2, 0, &LA[0][0]);
    STG(A,  rowBase, 1, 0, &LA[0][0]); STG(A,  rowBase, 3, 0, &LA[0][0]);
    VMW2_; FENCE_; __builtin_amdgcn_s_barrier();
    __builtin_amdgcn_sched_barrier(0);

    for (int t2 = 0; t2 < NT; t2 += 2) {
        KTILE(&LA[0][0], &LB[0][0], &LA[1][0], &LB[1][0], t2 + 1);
        KTILE(&LA[1][0], &LB[1][0], &LA[0][0], &LB[0][0], t2 + 2);
    }
    #undef KTILE
    #undef RDF
    #undef STG

    const int row0 = rowBase + wm * 128;
    const int c0   = colBase + wn * 64;
    {
        const int which = c0 >> 11;               // 0:q 1:k 2:v 3:gate
        const int h     = (c0 >> 7) & 15;
        const int d0    = c0 & 127;
        const int b     = row0 >> 12;
        const int bh    = b * NH_ + h;
        #pragma unroll
        for (int m = 0; m < 8; ++m) {
            int mr = (m >> 2) * 64 + (m & 3) * 16;
            int sr0 = (row0 & 4095) + mr + l4 * 4;
            #pragma unroll
            for (int n = 0; n < 4; ++n) {
                int nc = (n >> 1) * 32 + (n & 1) * 16;
                float x0 = acc[m][n][0], x1 = acc[m][n][1];
                float x2 = acc[m][n][2], x3 = acc[m][n][3];
                if (MODE == 0) {
                    float* cp = Cf + (size_t)(row0 + mr + l4 * 4) * N + c0 + nc + l15;
                    cp[0] = x0; cp[N] = x1; cp[2 * (size_t)N] = x2; cp[3 * (size_t)N] = x3;
                } else if (which == 3) {
                    int col_g = (c0 - 6144) + nc + l15;
                    ushort_t* gp = gateo + (size_t)(row0 + mr + l4 * 4) * H_ + col_g;
                    gp[0]       = f2bf(1.f / (1.f + __expf(-x0)));
                    gp[H_]      = f2bf(1.f / (1.f + __expf(-x1)));
                    gp[2 * H_]  = f2bf(1.f / (1.f + __expf(-x2)));
                    gp[3 * H_]  = f2bf(1.f / (1.f + __expf(-x3)));
                } else {
                    int d = d0 + nc + l15;
                    float s0 = x0 / (1.f + __expf(-x0));
                    float s1 = x1 / (1.f + __expf(-x1));
                    float s2 = x2 / (1.f + __expf(-x2));
                    float s3 = x3 / (1.f + __expf(-x3));
                    if (which == 0) {
                        ushort_t* qp = qo + ((size_t)bh * S_ + sr0) * HD_ + d;
                        qp[0]        = f2bf(s0);
                        qp[HD_]      = f2bf(s1);
                        qp[2 * HD_]  = f2bf(s2);
                        qp[3 * HD_]  = f2bf(s3);
                    } else if (which == 1) {
                        u16x4 pk = { f2bf(s0), f2bf(s1), f2bf(s2), f2bf(s3) };
                        ushort_t* kp = ko + ((size_t)bh * S_ + sr0) * HD_ + d;
                        kp[0] = pk[0]; kp[HD_] = pk[1]; kp[2 * HD_] = pk[2]; kp[3 * HD_] = pk[3];
                        *reinterpret_cast<u16x4*>(&kTo[((size_t)bh * HD_ + d) * S_ + sr0]) = pk;
                    } else {
                        float mk0 = mask[b * S_ + sr0],     mk1 = mask[b * S_ + sr0 + 1];
                        float mk2 = mask[b * S_ + sr0 + 2], mk3 = mask[b * S_ + sr0 + 3];
                        u16x4 pk = { f2bf(s0 * mk0), f2bf(s1 * mk1), f2bf(s2 * mk2), f2bf(s3 * mk3) };
                        *reinterpret_cast<u16x4*>(&vTo[((size_t)bh * HD_ + d) * S_ + sr0]) = pk;
                    }
                }
            }
        }
    }
}

// ---------------------------------------------------------------------------
// 128x128 MFMA GEMM (round-12 structure; for the small out-GEMM). f32 C.
// ---------------------------------------------------------------------------
__global__ __launch_bounds__(256, 2)
void gemm128(const ushort_t* __restrict__ A, const ushort_t* __restrict__ BT,
             int M, int N, int K, float* __restrict__ Cf)
{
    __shared__ __align__(16) ushort_t LA[2][8192];
    __shared__ __align__(16) ushort_t LB[2][8192];

    const int tid  = threadIdx.x;
    const int lane = tid & 63, wid = tid >> 6;
    const int wm = wid >> 1, wn = wid & 1;
    const int l15 = lane & 15, l4 = lane >> 4;
    const int trow = tid >> 3;
    const int xk   = (tid & 7) ^ (trow & 7);

    const int nwg = gridDim.x;
    const int lin = blockIdx.x;
    const int virt = (lin & 7) * (nwg >> 3) + (lin >> 3);
    const int NBX = N >> 7;
    const int by = virt / NBX, bx = virt - by * NBX;
    const int rowBase = by * 128, colBase = bx * 128;

    frag_cd acc[4][4];
    #pragma unroll
    for (int m = 0; m < 4; ++m)
        #pragma unroll
        for (int n = 0; n < 4; ++n) acc[m][n] = 0.f;

    frag_ab fa[4][2];
    frag_ab fb[4][2];

    #define RDF(Lp, row_, sl_) \
        (*reinterpret_cast<const frag_ab*>( \
            reinterpret_cast<const char*>(Lp) + (row_) * 128 + ((((sl_) ^ ((row_) & 7)) & 7) << 4)))
    #define STG(Gp, base_, i_, kt_, Lp) \
        gload_lds16((Gp) + (size_t)((base_) + (i_) * 32 + trow) * K + (kt_) + xk * 8, \
                    (Lp) + (i_) * 2048 + wid * 512)

    const int NT = K >> 6;
    int cur = 0;
    #pragma unroll
    for (int i = 0; i < 4; ++i) { STG(A, rowBase, i, 0, LA[0]); STG(BT, colBase, i, 0, LB[0]); }
    VMW0_; FENCE_; __builtin_amdgcn_s_barrier();
    __builtin_amdgcn_sched_barrier(0);

    for (int t = 0; t < NT; ++t) {
        const ushort_t* Ab = LA[cur];
        const ushort_t* Bb = LB[cur];
        ushort_t* An = LA[cur ^ 1];
        ushort_t* Bn = LB[cur ^ 1];
        const int ktn = (t + 1) << 6;
        const bool more = (t + 1) < NT;

        if (more) {
            #pragma unroll
            for (int i = 0; i < 4; ++i) { STG(A, rowBase, i, ktn, An); STG(BT, colBase, i, ktn, Bn); }
        }

        #pragma unroll
        for (int ni = 0; ni < 4; ++ni)
            #pragma unroll
            for (int ks = 0; ks < 2; ++ks)
                fb[ni][ks] = RDF(Bb, wn * 64 + ni * 16 + l15, ks * 4 + l4);
        #pragma unroll
        for (int mi = 0; mi < 4; ++mi)
            #pragma unroll
            for (int ks = 0; ks < 2; ++ks)
                fa[mi][ks] = RDF(Ab, wm * 64 + mi * 16 + l15, ks * 4 + l4);

        __builtin_amdgcn_s_setprio(1);
        #pragma unroll
        for (int mi = 0; mi < 4; ++mi)
            #pragma unroll
            for (int ni = 0; ni < 4; ++ni)
                #pragma unroll
                for (int ks = 0; ks < 2; ++ks)
                    acc[mi][ni] = __builtin_amdgcn_mfma_f32_16x16x32_bf16(
                        fa[mi][ks], fb[ni][ks], acc[mi][ni], 0, 0, 0);
        __builtin_amdgcn_s_setprio(0);

        VMW0_; FENCE_; __builtin_amdgcn_s_barrier();
        __builtin_amdgcn_sched_barrier(0);
        cur ^= 1;
    }
    #undef RDF
    #undef STG

    const int row0 = rowBase + wm * 64;
    const int c0   = colBase + wn * 64;
    #pragma unroll
    for (int m = 0; m < 4; ++m)
        #pragma unroll
        for (int n = 0; n < 4; ++n)
            #pragma unroll
            for (int r = 0; r < 4; ++r) {
                int row = row0 + m * 16 + l4 * 4 + r;
                int col = c0 + n * 16 + l15;
                Cf[(size_t)row * N + col] = acc[m][n][r];
            }
}

// ---------------------------------------------------------------------------
// Per-chunk KV state contribution (MFMA, transposed output) — unchanged.
// ---------------------------------------------------------------------------
__global__ __launch_bounds__(256)
void kv_chunk_mfma(const ushort_t* __restrict__ kT, const ushort_t* __restrict__ vT,
                   const float* __restrict__ slope, ushort_t* __restrict__ kvT)
{
    const int c = blockIdx.x, bh = blockIdx.y;
    const float s = slope[bh & 15];
    const int tid = threadIdx.x, lane = tid & 63, w = tid >> 6;
    const int l15 = lane & 15, l4 = lane >> 4;
    __shared__ float dec[BLOCK_];
    __shared__ __align__(16) ushort_t VTl[128 * 64];
    __shared__ __align__(16) ushort_t KTl[128 * 64];
    dec[tid] = __expf(-s * (float)(BLOCK_ - 1 - tid));

    frag_cd acc[2][8];
    #pragma unroll
    for (int mf = 0; mf < 2; ++mf)
        #pragma unroll
        for (int df = 0; df < 8; ++df) acc[mf][df] = 0.f;

    for (int nt = 0; nt < 4; ++nt) {
        __syncthreads();
        #pragma unroll
        for (int i = 0; i < 4; ++i) {
            int u = tid + i * 256;
            int row = u >> 3, slot = u & 7;
            size_t gsrc = ((size_t)bh * HD_ + row) * S_ + c * BLOCK_ + nt * 64 + slot * 8;
            frag_ab v8 = *reinterpret_cast<const frag_ab*>(vT + gsrc);
            *reinterpret_cast<frag_ab*>((char*)VTl + row * 128 + ((slot * 16) ^ ((row & 7) << 4))) = v8;
            frag_ab k8 = *reinterpret_cast<const frag_ab*>(kT + gsrc);
            frag_ab kd;
            #pragma unroll
            for (int j = 0; j < 8; ++j)
                kd[j] = (short)f2bf(bf2f((ushort_t)k8[j]) * dec[nt * 64 + slot * 8 + j]);
            *reinterpret_cast<frag_ab*>((char*)KTl + row * 128 + ((slot * 16) ^ ((row & 7) << 4))) = kd;
        }
        __syncthreads();
        #pragma unroll
        for (int ks = 0; ks < 2; ++ks) {
            frag_ab a[2];
            #pragma unroll
            for (int mf = 0; mf < 2; ++mf)
                a[mf] = *reinterpret_cast<const frag_ab*>(
                    (char*)VTl + (w * 32 + mf * 16 + l15) * 128 + ((ks * 64 + l4 * 16) ^ ((l15 & 7) << 4)));
            #pragma unroll
            for (int df = 0; df < 8; ++df) {
                frag_ab bk = *reinterpret_cast<const frag_ab*>(
                    (char*)KTl + (df * 16 + l15) * 128 + ((ks * 64 + l4 * 16) ^ ((l15 & 7) << 4)));
                acc[0][df] = __builtin_amdgcn_mfma_f32_16x16x32_bf16(a[0], bk, acc[0][df], 0, 0, 0);
                acc[1][df] = __builtin_amdgcn_mfma_f32_16x16x32_bf16(a[1], bk, acc[1][df], 0, 0, 0);
            }
        }
    }
    ushort_t* out = kvT + ((size_t)bh * NC_ + c) * 16384;
    #pragma unroll
    for (int mf = 0; mf < 2; ++mf)
        #pragma unroll
        for (int df = 0; df < 8; ++df)
            #pragma unroll
            for (int r = 0; r < 4; ++r) {
                int e = w * 32 + mf * 16 + l4 * 4 + r;
                int d = df * 16 + l15;
                out[e * 128 + d] = f2bf(acc[mf][df][r]);
            }
}

// ---------------------------------------------------------------------------
// Prefix scan over chunks — unchanged.
// ---------------------------------------------------------------------------
__global__ __launch_bounds__(256)
void kv_scan_kernel(const float* __restrict__ slope, const ushort_t* __restrict__ kvT,
                    ushort_t* __restrict__ sT)
{
    const int es = blockIdx.x, bh = blockIdx.y;
    const float s = slope[bh & 15];
    const float bd = __expf(-s * (float)BLOCK_);
    const int tid = threadIdx.x;
    float st[16];
    #pragma unroll
    for (int i = 0; i < 16; ++i) st[i] = 0.f;
    for (int c = 0; c < NC_; ++c) {
        const ushort_t* p = kvT + ((size_t)bh * NC_ + c) * 16384;
        ushort_t* qp = sT + ((size_t)bh * NC_ + c) * 16384;
        #pragma unroll
        for (int i = 0; i < 16; ++i) {
            int lin = tid + i * 256;
            int off = (lin >> 5) * 128 + es * 32 + (lin & 31);
            float x = bf2f(p[off]);
            qp[off] = f2bf(st[i]);
            st[i] = bd * st[i] + x;
        }
    }
}

// ---------------------------------------------------------------------------
// MFMA attention per chunk — unchanged.
// ---------------------------------------------------------------------------
__global__ __launch_bounds__(512)
void attn_mfma(const ushort_t* __restrict__ q, const ushort_t* __restrict__ k,
               const ushort_t* __restrict__ vT, const ushort_t* __restrict__ sT,
               const float* __restrict__ slope, float* __restrict__ o)
{
    const int c = blockIdx.x, bh = blockIdx.y;
    const int h = bh & 15, b = bh >> 4;
    const float s = slope[h];
    const int tid = threadIdx.x, lane = tid & 63, w = tid >> 6;
    const int l15 = lane & 15, l4 = lane >> 4;

    __shared__ __align__(16) ushort_t SH[16384];
    __shared__ __align__(16) ushort_t P[8][2048];

    frag_ab aq[2][4];
    #pragma unroll
    for (int mf = 0; mf < 2; ++mf)
        #pragma unroll
        for (int ks = 0; ks < 4; ++ks) {
            int row = c * BLOCK_ + w * 32 + mf * 16 + l15;
            aq[mf][ks] = *reinterpret_cast<const frag_ab*>(
                q + ((size_t)bh * S_ + row) * HD_ + ks * 32 + l4 * 8);
        }

    frag_cd oa[2][8];
    #pragma unroll
    for (int mf = 0; mf < 2; ++mf)
        #pragma unroll
        for (int ef = 0; ef < 8; ++ef) oa[mf][ef] = 0.f;

    const int wrow = w * 32;
    for (int nt = 0; nt < 4; ++nt) {
        __syncthreads();
        #pragma unroll
        for (int i = 0; i < 2; ++i) {
            int u = tid + i * 512;
            int n = u >> 4, slot = u & 15;
            frag_ab k8 = *reinterpret_cast<const frag_ab*>(
                k + ((size_t)bh * S_ + c * BLOCK_ + nt * 64 + n) * HD_ + slot * 8);
            *reinterpret_cast<frag_ab*>((char*)SH + n * 256 + ((slot * 16) ^ ((n & 7) << 4))) = k8;
        }
        #pragma unroll
        for (int i = 0; i < 2; ++i) {
            int u = tid + i * 512;
            int e = u >> 3, slot = u & 7;
            frag_ab v8 = *reinterpret_cast<const frag_ab*>(
                vT + ((size_t)bh * HD_ + e) * S_ + c * BLOCK_ + nt * 64 + slot * 8);
            *reinterpret_cast<frag_ab*>((char*)SH + 16384 + e * 128 + ((slot * 16) ^ ((e & 7) << 4))) = v8;
        }
        __syncthreads();
        if (nt * 64 > wrow + 31) continue;

        frag_cd pacc[2][4];
        #pragma unroll
        for (int mf = 0; mf < 2; ++mf)
            #pragma unroll
            for (int nf = 0; nf < 4; ++nf) pacc[mf][nf] = 0.f;
        #pragma unroll
        for (int ks = 0; ks < 4; ++ks)
            #pragma unroll
            for (int nf = 0; nf < 4; ++nf) {
                frag_ab bk = *reinterpret_cast<const frag_ab*>(
                    (char*)SH + (nf * 16 + l15) * 256 + ((ks * 64 + l4 * 16) ^ ((l15 & 7) << 4)));
                pacc[0][nf] = __builtin_amdgcn_mfma_f32_16x16x32_bf16(aq[0][ks], bk, pacc[0][nf], 0, 0, 0);
                pacc[1][nf] = __builtin_amdgcn_mfma_f32_16x16x32_bf16(aq[1][ks], bk, pacc[1][nf], 0, 0, 0);
            }
        #pragma unroll
        for (int mf = 0; mf < 2; ++mf)
            #pragma unroll
            for (int nf = 0; nf < 4; ++nf)
                #pragma unroll
                for (int r = 0; r < 4; ++r) {
                    int m = mf * 16 + l4 * 4 + r;
                    int mrow = wrow + m;
                    int ncol = nt * 64 + nf * 16 + l15;
                    float pv = 0.f;
                    if (mrow >= ncol) pv = pacc[mf][nf][r] * __expf(s * (float)(ncol - mrow));
                    *reinterpret_cast<ushort_t*>(
                        (char*)&P[w][0] + m * 128 + (((nf * 16 + l15) * 2) ^ ((m & 7) << 4))) = f2bf(pv);
                }
        __builtin_amdgcn_sched_barrier(0);
        #pragma unroll
        for (int ks = 0; ks < 2; ++ks) {
            frag_ab ap[2];
            #pragma unroll
            for (int mf = 0; mf < 2; ++mf)
                ap[mf] = *reinterpret_cast<const frag_ab*>(
                    (char*)&P[w][0] + (mf * 16 + l15) * 128 + ((ks * 64 + l4 * 16) ^ ((l15 & 7) << 4)));
            #pragma unroll
            for (int ef = 0; ef < 8; ++ef) {
                frag_ab bv = *reinterpret_cast<const frag_ab*>(
                    (char*)SH + 16384 + (ef * 16 + l15) * 128 + ((ks * 64 + l4 * 16) ^ ((l15 & 7) << 4)));
                oa[0][ef] = __builtin_amdgcn_mfma_f32_16x16x32_bf16(ap[0], bv, oa[0][ef], 0, 0, 0);
                oa[1][ef] = __builtin_amdgcn_mfma_f32_16x16x32_bf16(ap[1], bv, oa[1][ef], 0, 0, 0);
            }
        }
    }

    __syncthreads();
    #pragma unroll
    for (int i = 0; i < 4; ++i) {
        int u = tid + i * 512;
        int e = u >> 4, slot = u & 15;
        frag_ab s8 = *reinterpret_cast<const frag_ab*>(
            sT + ((size_t)(bh * NC_ + c)) * 16384 + e * 128 + slot * 8);
        *reinterpret_cast<frag_ab*>((char*)SH + e * 256 + ((slot * 16) ^ ((e & 7) << 4))) = s8;
    }
    __syncthreads();
    #pragma unroll
    for (int mf = 0; mf < 2; ++mf) {
        float qd = __expf(-s * (float)(wrow + mf * 16 + l15 + 1));
        #pragma unroll
        for (int ks = 0; ks < 4; ++ks) {
            frag_ab v = aq[mf][ks];
            #pragma unroll
            for (int j = 0; j < 8; ++j)
                v[j] = (short)f2bf(bf2f((ushort_t)v[j]) * qd);
            aq[mf][ks] = v;
        }
    }
    #pragma unroll
    for (int ks = 0; ks < 4; ++ks)
        #pragma unroll
        for (int ef = 0; ef < 8; ++ef) {
            frag_ab bs = *reinterpret_cast<const frag_ab*>(
                (char*)SH + (ef * 16 + l15) * 256 + ((ks * 64 + l4 * 16) ^ ((l15 & 7) << 4)));
            oa[0][ef] = __builtin_amdgcn_mfma_f32_16x16x32_bf16(aq[0][ks], bs, oa[0][ef], 0, 0, 0);
            oa[1][ef] = __builtin_amdgcn_mfma_f32_16x16x32_bf16(aq[1][ks], bs, oa[1][ef], 0, 0, 0);
        }
    #pragma unroll
    for (int mf = 0; mf < 2; ++mf)
        #pragma unroll
        for (int ef = 0; ef < 8; ++ef)
            #pragma unroll
            for (int r = 0; r < 4; ++r) {
                int row = c * BLOCK_ + wrow + mf * 16 + l4 * 4 + r;
                int col = h * HD_ + ef * 16 + l15;
                o[((size_t)(b * S_ + row)) * H_ + col] = oa[mf][ef][r];
            }
}

// ---------------------------------------------------------------------------
// RMSNorm * norm_weight * gate — unchanged.
// ---------------------------------------------------------------------------
__global__ __launch_bounds__(256)
void norm_gate_kernel(const float* __restrict__ o, const ushort_t* __restrict__ gate,
                      const float* __restrict__ nw, ushort_t* __restrict__ on)
{
    const int row = blockIdx.x;
    const int tid = threadIdx.x;
    const float* orow = o + (size_t)row * H_;
    const ushort_t* grow = gate + (size_t)row * H_;
    ushort_t* onrow = on + (size_t)row * H_;
    float vals[8];
    float ss = 0.f;
    #pragma unroll
    for (int i = 0; i < 8; ++i) {
        vals[i] = orow[tid + i * 256];
        ss += vals[i] * vals[i];
    }
    __shared__ float red[256];
    red[tid] = ss;
    __syncthreads();
    #pragma unroll
    for (int st = 128; st > 0; st >>= 1) {
        if (tid < st) red[tid] += red[tid + st];
        __syncthreads();
    }
    float scale = rsqrtf(red[0] * (1.f / (float)H_) + EPS_);
    #pragma unroll
    for (int i = 0; i < 8; ++i) {
        int cidx = tid + i * 256;
        onrow[cidx] = f2bf(vals[i] * scale * nw[cidx] * bf2f(grow[cidx]));
    }
}

// ---------------------------------------------------------------------------
extern "C" void kernel_launch(void* const* d_in, const int* in_sizes, int n_in,
                              void* d_out, int out_size, void* d_ws, size_t ws_size,
                              hipStream_t stream)
{
    const float* hidden = (const float*)d_in[0];
    const float* mask   = (const float*)d_in[1];
    const float* slope  = (const float*)d_in[2];
    const float* w_qkv  = (const float*)d_in[3];
    const float* w_gate = (const float*)d_in[4];
    const float* w_out  = (const float*)d_in[5];
    const float* nw     = (const float*)d_in[6];

    const size_t MH = (size_t)M_ * H_;                 // 16,777,216 elements
    ushort_t* hid_bf  = (ushort_t*)d_ws;
    ushort_t* on_ws   = hid_bf;
    // r1: wqkvT (6144x2048) + wgateT (2048x2048) contiguous = BT[8192][2048]
    ushort_t* wqkvT   = hid_bf + MH;
    ushort_t* wgateT  = wqkvT + (size_t)6144 * 2048;
    ushort_t* kvT_ws  = wqkvT;
    ushort_t* sT_ws   = wqkvT + MH / 2;
    ushort_t* woutT   = wqkvT;
    ushort_t* q_ws    = hid_bf + 2 * MH;
    ushort_t* k_ws    = q_ws + MH;
    ushort_t* vT_ws   = k_ws + MH;
    ushort_t* gate_ws = vT_ws + MH;
    ushort_t* kT_ws   = (ushort_t*)d_out;
    float*    o_f32   = (float*)d_out;

    dim3 blk(256);
    cast_bf16_kernel<<<(MH / 4) / 256, blk, 0, stream>>>(hidden, hid_bf);
    transpose_cast_kernel<<<dim3(6144 / 32, 2048 / 32), blk, 0, stream>>>(w_qkv, wqkvT, 2048, 6144);
    transpose_cast_kernel<<<dim3(2048 / 32, 2048 / 32), blk, 0, stream>>>(w_gate, wgateT, 2048, 2048);
    // 1+2. combined qkv+gate GEMM (N=8192), static-dbuf 2x-unrolled schedule
    gemm256<2><<<dim3((M_ / 256) * (8192 / 256)), dim3(512), 0, stream>>>(
        hid_bf, wqkvT, M_, 8192, 2048,
        nullptr, q_ws, k_ws, kT_ws, vT_ws, gate_ws, mask);
    // 3. per-chunk KV^T contributions
    kv_chunk_mfma<<<dim3(NC_, B_ * NH_), blk, 0, stream>>>(kT_ws, vT_ws, slope, kvT_ws);
    // 4. prefix scan -> S^T per chunk
    kv_scan_kernel<<<dim3(4, B_ * NH_), blk, 0, stream>>>(slope, kvT_ws, sT_ws);
    // 5. attention -> o f32 into d_out
    attn_mfma<<<dim3(NC_, B_ * NH_), dim3(512), 0, stream>>>(
        q_ws, k_ws, vT_ws, sT_ws, slope, o_f32);
    // prep final weight (kvT dead; sT untouched)
    transpose_cast_kernel<<<dim3(2048 / 32, 2048 / 32), blk, 0, stream>>>(w_out, woutT, 2048, 2048);
    // 6. RMSNorm * nw * gate -> bf16 o_n
    norm_gate_kernel<<<M_, blk, 0, stream>>>(o_f32, gate_ws, nw, on_ws);
    // 7. out = o_n @ w_out (128^2 structure, 2 blocks/CU)
    gemm128<<<dim3((M_ / 128) * (2048 / 128)), blk, 0, stream>>>(
        on_ws, woutT, M_, 2048, 2048, (float*)d_out);
}

// Round 15
// 544.412 us; speedup vs baseline: 1.0326x; 1.0326x over previous
//
#include <hip/hip_runtime.h>
#include <cstdint>

#define B_ 2
#define S_ 4096
#define H_ 2048
#define NH_ 16
#define HD_ 128
#define BLOCK_ 256
#define NC_ (S_/BLOCK_)   // 16
#define M_ (B_*S_)        // 8192
#define EPS_ 1e-5f

typedef unsigned short ushort_t;
typedef unsigned short u16x4 __attribute__((ext_vector_type(4)));
typedef short frag_ab __attribute__((ext_vector_type(8)));   // 8 bf16 (4 VGPRs)
typedef float frag_cd __attribute__((ext_vector_type(4)));   // 4 f32

static __device__ inline float bf2f(ushort_t u) {
    union { unsigned int i; float f; } x;
    x.i = ((unsigned int)u) << 16;
    return x.f;
}
static __device__ inline ushort_t f2bf(float f) {
    union { float f; unsigned int i; } x;
    x.f = f;
    unsigned int r = x.i + 0x7fffu + ((x.i >> 16) & 1u);
    return (ushort_t)(r >> 16);
}

// async global->LDS, 16B per lane; LDS dest is wave-uniform base + lane*16
static __device__ __forceinline__ void gload_lds16(const ushort_t* g, ushort_t* l) {
    __builtin_amdgcn_global_load_lds(
        (__attribute__((address_space(1))) void*)(uintptr_t)g,
        (__attribute__((address_space(3))) void*)l,
        16, 0, 0);
}

#define FENCE_ asm volatile("" ::: "memory")
#define VMW2_  asm volatile("s_waitcnt vmcnt(2)" ::: "memory")
#define VMW4_  asm volatile("s_waitcnt vmcnt(4)" ::: "memory")
#define VMW0_  asm volatile("s_waitcnt vmcnt(0)" ::: "memory")

// ---------------------------------------------------------------------------
// Prep: f32 -> bf16 elementwise cast (hidden).
// ---------------------------------------------------------------------------
__global__ __launch_bounds__(256)
void cast_bf16_kernel(const float* __restrict__ in, ushort_t* __restrict__ out)
{
    int i = blockIdx.x * 256 + threadIdx.x;
    float4 v = reinterpret_cast<const float4*>(in)[i];
    u16x4 o = { f2bf(v.x), f2bf(v.y), f2bf(v.z), f2bf(v.w) };
    *reinterpret_cast<u16x4*>(&out[(size_t)i * 4]) = o;
}

// ---------------------------------------------------------------------------
// Prep: W[K][N] f32 -> WT[N][K] bf16 (tiled transpose+cast).
// ---------------------------------------------------------------------------
__global__ __launch_bounds__(256)
void transpose_cast_kernel(const float* __restrict__ W, ushort_t* __restrict__ WT,
                           int K, int N)
{
    __shared__ float t[32][33];
    const int kb = blockIdx.y * 32, nb = blockIdx.x * 32;
    const int tx = threadIdx.x & 31, ty = threadIdx.x >> 5;  // 32 x 8
    #pragma unroll
    for (int i = 0; i < 4; ++i)
        t[ty + i * 8][tx] = W[(size_t)(kb + ty + i * 8) * N + nb + tx];
    __syncthreads();
    #pragma unroll
    for (int i = 0; i < 4; ++i)
        WT[(size_t)(nb + ty + i * 8) * K + kb + tx] = f2bf(t[tx][ty + i * 8]);
}

// ---------------------------------------------------------------------------
// 256x256 MFMA GEMM, 4 MFMA clusters + 2 barriers per K-tile (round-8 exact:
// best measured config, 544 us total). BK=64, dbuf LDS, 512 thr = 8 waves.
// Staging order/iter: B0,B1 | B2,B3 | A0,A2 | A1,A3 (2 gload_lds / cluster).
//   C2 end: vmcnt(4) drains A1,A3(t) [leaves 4 B(t+1)] -> MID barrier
//   C4 end: vmcnt(2) drains B0-3,A0,A2(t+1) [leaves A1,A3(t+1)] -> END barrier
// ---------------------------------------------------------------------------
template<int MODE>
__global__ __launch_bounds__(512, 2)
void gemm256(const ushort_t* __restrict__ A, const ushort_t* __restrict__ BT,
             int M, int N, int K,
             float* __restrict__ Cf,
             ushort_t* __restrict__ qo, ushort_t* __restrict__ ko,
             ushort_t* __restrict__ kTo, ushort_t* __restrict__ vTo,
             ushort_t* __restrict__ gateo, const float* __restrict__ mask)
{
    __shared__ __align__(16) ushort_t LA[2][16384];   // 2 x 32KB  [256 rows][64 k]
    __shared__ __align__(16) ushort_t LB[2][16384];   // 2 x 32KB

    const int tid  = threadIdx.x;
    const int lane = tid & 63, wid = tid >> 6;
    const int wm = wid >> 2, wn = wid & 3;
    const int l15 = lane & 15, l4 = lane >> 4;
    const int trow = tid >> 3;                 // staging row within 64-row half
    const int xk   = (tid & 7) ^ (trow & 7);   // inverse-swizzled k-slot

    // XCD-aware bijective swizzle (gridDim.x % 8 == 0 by launch config)
    const int nwg = gridDim.x;
    const int lin = blockIdx.x;
    const int virt = (lin & 7) * (nwg >> 3) + (lin >> 3);
    const int NBX = N >> 8;
    const int by = virt / NBX, bx = virt - by * NBX;
    const int rowBase = by * 256, colBase = bx * 256;

    frag_cd acc[8][4];
    #pragma unroll
    for (int m = 0; m < 8; ++m)
        #pragma unroll
        for (int n = 0; n < 4; ++n) acc[m][n] = 0.f;

    frag_ab fa[4][2];      // current mh's A frags [mi][ks]
    frag_ab fb[2][2][2];   // B frags [nh][ni][ks]

    // swizzled frag read: row stride 128B, 8 x 16B slots, slot ^= row&7
    #define RDF(Lp, row_, sl_) \
        (*reinterpret_cast<const frag_ab*>( \
            reinterpret_cast<const char*>(Lp) + (row_) * 128 + ((((sl_) ^ ((row_) & 7)) & 7) << 4)))
    // stage one 64-row half-tile
    #define STG(Gp, base_, i_, kt_, Lp) \
        gload_lds16((Gp) + (size_t)((base_) + (i_) * 64 + trow) * K + (kt_) + xk * 8, \
                    (Lp) + (i_) * 4096 + wid * 512)

    const int NT = K >> 6;
    int cur = 0;
    // prologue: stage tile 0 in canonical order, drain first 6, barrier
    STG(BT, colBase, 0, 0, LB[0]); STG(BT, colBase, 1, 0, LB[0]);
    STG(BT, colBase, 2, 0, LB[0]); STG(BT, colBase, 3, 0, LB[0]);
    STG(A,  rowBase, 0, 0, LA[0]); STG(A,  rowBase, 2, 0, LA[0]);
    STG(A,  rowBase, 1, 0, LA[0]); STG(A,  rowBase, 3, 0, LA[0]);
    VMW2_; FENCE_; __builtin_amdgcn_s_barrier();
    __builtin_amdgcn_sched_barrier(0);

    for (int t = 0; t < NT; ++t) {
        const ushort_t* Ab = LA[cur];
        const ushort_t* Bb = LB[cur];
        ushort_t* An = LA[cur ^ 1];
        ushort_t* Bn = LB[cur ^ 1];
        const int ktn = (t + 1) << 6;
        const bool more = (t + 1) < NT;

        // ---- C1: read fa0+fb0, stage B0,B1(t+1), MFMA top-left ----
        #pragma unroll
        for (int mi = 0; mi < 4; ++mi)
            #pragma unroll
            for (int ks = 0; ks < 2; ++ks)
                fa[mi][ks] = RDF(Ab, wm * 128 + mi * 16 + l15, ks * 4 + l4);
        #pragma unroll
        for (int ni = 0; ni < 2; ++ni)
            #pragma unroll
            for (int ks = 0; ks < 2; ++ks)
                fb[0][ni][ks] = RDF(Bb, wn * 64 + ni * 16 + l15, ks * 4 + l4);
        if (more) { STG(BT, colBase, 0, ktn, Bn); STG(BT, colBase, 1, ktn, Bn); }
        __builtin_amdgcn_s_setprio(1);
        #pragma unroll
        for (int mi = 0; mi < 4; ++mi)
            #pragma unroll
            for (int ni = 0; ni < 2; ++ni)
                #pragma unroll
                for (int ks = 0; ks < 2; ++ks)
                    acc[mi][ni] = __builtin_amdgcn_mfma_f32_16x16x32_bf16(
                        fa[mi][ks], fb[0][ni][ks], acc[mi][ni], 0, 0, 0);
        __builtin_amdgcn_s_setprio(0);

        // ---- C2: read fb1, stage B2,B3(t+1), MFMA top-right; mid sync ----
        #pragma unroll
        for (int ni = 0; ni < 2; ++ni)
            #pragma unroll
            for (int ks = 0; ks < 2; ++ks)
                fb[1][ni][ks] = RDF(Bb, wn * 64 + 32 + ni * 16 + l15, ks * 4 + l4);
        if (more) { STG(BT, colBase, 2, ktn, Bn); STG(BT, colBase, 3, ktn, Bn); }
        __builtin_amdgcn_s_setprio(1);
        #pragma unroll
        for (int mi = 0; mi < 4; ++mi)
            #pragma unroll
            for (int ni = 0; ni < 2; ++ni)
                #pragma unroll
                for (int ks = 0; ks < 2; ++ks)
                    acc[mi][2 + ni] = __builtin_amdgcn_mfma_f32_16x16x32_bf16(
                        fa[mi][ks], fb[1][ni][ks], acc[mi][2 + ni], 0, 0, 0);
        __builtin_amdgcn_s_setprio(0);
        if (more) { VMW4_; } else { VMW0_; }
        FENCE_; __builtin_amdgcn_s_barrier();
        __builtin_amdgcn_sched_barrier(0);

        // ---- C3: read fa1 (A1/A3 now visible), stage A0,A2(t+1), MFMA bottom-left ----
        #pragma unroll
        for (int mi = 0; mi < 4; ++mi)
            #pragma unroll
            for (int ks = 0; ks < 2; ++ks)
                fa[mi][ks] = RDF(Ab, wm * 128 + 64 + mi * 16 + l15, ks * 4 + l4);
        if (more) { STG(A, rowBase, 0, ktn, An); STG(A, rowBase, 2, ktn, An); }
        __builtin_amdgcn_s_setprio(1);
        #pragma unroll
        for (int mi = 0; mi < 4; ++mi)
            #pragma unroll
            for (int ni = 0; ni < 2; ++ni)
                #pragma unroll
                for (int ks = 0; ks < 2; ++ks)
                    acc[4 + mi][ni] = __builtin_amdgcn_mfma_f32_16x16x32_bf16(
                        fa[mi][ks], fb[0][ni][ks], acc[4 + mi][ni], 0, 0, 0);
        __builtin_amdgcn_s_setprio(0);

        // ---- C4: stage A1,A3(t+1), MFMA bottom-right; end sync ----
        if (more) { STG(A, rowBase, 1, ktn, An); STG(A, rowBase, 3, ktn, An); }
        __builtin_amdgcn_s_setprio(1);
        #pragma unroll
        for (int mi = 0; mi < 4; ++mi)
            #pragma unroll
            for (int ni = 0; ni < 2; ++ni)
                #pragma unroll
                for (int ks = 0; ks < 2; ++ks)
                    acc[4 + mi][2 + ni] = __builtin_amdgcn_mfma_f32_16x16x32_bf16(
                        fa[mi][ks], fb[1][ni][ks], acc[4 + mi][2 + ni], 0, 0, 0);
        __builtin_amdgcn_s_setprio(0);
        if (more) { VMW2_; }
        FENCE_; __builtin_amdgcn_s_barrier();
        __builtin_amdgcn_sched_barrier(0);

        cur ^= 1;
    }
    #undef RDF
    #undef STG

    // ---------------- epilogue ----------------
    const int row0 = rowBase + wm * 128;
    const int c0   = colBase + wn * 64;
    if (MODE == 0) {
        #pragma unroll
        for (int m = 0; m < 8; ++m) {
            int mr = (m >> 2) * 64 + (m & 3) * 16;
            #pragma unroll
            for (int n = 0; n < 4; ++n) {
                int nc = (n >> 1) * 32 + (n & 1) * 16;
                #pragma unroll
                for (int r = 0; r < 4; ++r) {
                    int row = row0 + mr + l4 * 4 + r;
                    int col = c0 + nc + l15;
                    Cf[(size_t)row * N + col] = acc[m][n][r];
                }
            }
        }
    } else {
        const int which = c0 >> 11;               // 0:q 1:k 2:v 3:gate
        const int h     = (c0 >> 7) & 15;
        const int d0    = c0 & 127;
        const int b     = row0 >> 12;
        const int bh    = b * NH_ + h;
        #pragma unroll
        for (int m = 0; m < 8; ++m) {
            int mr = (m >> 2) * 64 + (m & 3) * 16;
            int sr0 = (row0 & 4095) + mr + l4 * 4;
            #pragma unroll
            for (int n = 0; n < 4; ++n) {
                int nc = (n >> 1) * 32 + (n & 1) * 16;
                float x0 = acc[m][n][0], x1 = acc[m][n][1];
                float x2 = acc[m][n][2], x3 = acc[m][n][3];
                if (which == 3) {
                    int col_g = (c0 - 6144) + nc + l15;
                    ushort_t* gp = gateo + (size_t)(row0 + mr + l4 * 4) * H_ + col_g;
                    gp[0]       = f2bf(1.f / (1.f + __expf(-x0)));
                    gp[H_]      = f2bf(1.f / (1.f + __expf(-x1)));
                    gp[2 * H_]  = f2bf(1.f / (1.f + __expf(-x2)));
                    gp[3 * H_]  = f2bf(1.f / (1.f + __expf(-x3)));
                } else {
                    int d = d0 + nc + l15;
                    float s0 = x0 / (1.f + __expf(-x0));
                    float s1 = x1 / (1.f + __expf(-x1));
                    float s2 = x2 / (1.f + __expf(-x2));
                    float s3 = x3 / (1.f + __expf(-x3));
                    if (which == 0) {
                        ushort_t* qp = qo + ((size_t)bh * S_ + sr0) * HD_ + d;
                        qp[0]        = f2bf(s0);
                        qp[HD_]      = f2bf(s1);
                        qp[2 * HD_]  = f2bf(s2);
                        qp[3 * HD_]  = f2bf(s3);
                    } else if (which == 1) {
                        u16x4 pk = { f2bf(s0), f2bf(s1), f2bf(s2), f2bf(s3) };
                        ushort_t* kp = ko + ((size_t)bh * S_ + sr0) * HD_ + d;
                        kp[0] = pk[0]; kp[HD_] = pk[1]; kp[2 * HD_] = pk[2]; kp[3 * HD_] = pk[3];
                        *reinterpret_cast<u16x4*>(&kTo[((size_t)bh * HD_ + d) * S_ + sr0]) = pk;
                    } else {
                        float mk0 = mask[b * S_ + sr0],     mk1 = mask[b * S_ + sr0 + 1];
                        float mk2 = mask[b * S_ + sr0 + 2], mk3 = mask[b * S_ + sr0 + 3];
                        u16x4 pk = { f2bf(s0 * mk0), f2bf(s1 * mk1), f2bf(s2 * mk2), f2bf(s3 * mk3) };
                        *reinterpret_cast<u16x4*>(&vTo[((size_t)bh * HD_ + d) * S_ + sr0]) = pk;
                    }
                }
            }
        }
    }
}

// ---------------------------------------------------------------------------
// Per-chunk KV state contribution (MFMA, transposed output) — unchanged.
// ---------------------------------------------------------------------------
__global__ __launch_bounds__(256)
void kv_chunk_mfma(const ushort_t* __restrict__ kT, const ushort_t* __restrict__ vT,
                   const float* __restrict__ slope, ushort_t* __restrict__ kvT)
{
    const int c = blockIdx.x, bh = blockIdx.y;
    const float s = slope[bh & 15];
    const int tid = threadIdx.x, lane = tid & 63, w = tid >> 6;
    const int l15 = lane & 15, l4 = lane >> 4;
    __shared__ float dec[BLOCK_];
    __shared__ __align__(16) ushort_t VTl[128 * 64];
    __shared__ __align__(16) ushort_t KTl[128 * 64];
    dec[tid] = __expf(-s * (float)(BLOCK_ - 1 - tid));

    frag_cd acc[2][8];
    #pragma unroll
    for (int mf = 0; mf < 2; ++mf)
        #pragma unroll
        for (int df = 0; df < 8; ++df) acc[mf][df] = 0.f;

    for (int nt = 0; nt < 4; ++nt) {
        __syncthreads();
        #pragma unroll
        for (int i = 0; i < 4; ++i) {
            int u = tid + i * 256;
            int row = u >> 3, slot = u & 7;
            size_t gsrc = ((size_t)bh * HD_ + row) * S_ + c * BLOCK_ + nt * 64 + slot * 8;
            frag_ab v8 = *reinterpret_cast<const frag_ab*>(vT + gsrc);
            *reinterpret_cast<frag_ab*>((char*)VTl + row * 128 + ((slot * 16) ^ ((row & 7) << 4))) = v8;
            frag_ab k8 = *reinterpret_cast<const frag_ab*>(kT + gsrc);
            frag_ab kd;
            #pragma unroll
            for (int j = 0; j < 8; ++j)
                kd[j] = (short)f2bf(bf2f((ushort_t)k8[j]) * dec[nt * 64 + slot * 8 + j]);
            *reinterpret_cast<frag_ab*>((char*)KTl + row * 128 + ((slot * 16) ^ ((row & 7) << 4))) = kd;
        }
        __syncthreads();
        #pragma unroll
        for (int ks = 0; ks < 2; ++ks) {
            frag_ab a[2];
            #pragma unroll
            for (int mf = 0; mf < 2; ++mf)
                a[mf] = *reinterpret_cast<const frag_ab*>(
                    (char*)VTl + (w * 32 + mf * 16 + l15) * 128 + ((ks * 64 + l4 * 16) ^ ((l15 & 7) << 4)));
            #pragma unroll
            for (int df = 0; df < 8; ++df) {
                frag_ab bk = *reinterpret_cast<const frag_ab*>(
                    (char*)KTl + (df * 16 + l15) * 128 + ((ks * 64 + l4 * 16) ^ ((l15 & 7) << 4)));
                acc[0][df] = __builtin_amdgcn_mfma_f32_16x16x32_bf16(a[0], bk, acc[0][df], 0, 0, 0);
                acc[1][df] = __builtin_amdgcn_mfma_f32_16x16x32_bf16(a[1], bk, acc[1][df], 0, 0, 0);
            }
        }
    }
    ushort_t* out = kvT + ((size_t)bh * NC_ + c) * 16384;
    #pragma unroll
    for (int mf = 0; mf < 2; ++mf)
        #pragma unroll
        for (int df = 0; df < 8; ++df)
            #pragma unroll
            for (int r = 0; r < 4; ++r) {
                int e = w * 32 + mf * 16 + l4 * 4 + r;
                int d = df * 16 + l15;
                out[e * 128 + d] = f2bf(acc[mf][df][r]);
            }
}

// ---------------------------------------------------------------------------
// Prefix scan over chunks — unchanged.
// ---------------------------------------------------------------------------
__global__ __launch_bounds__(256)
void kv_scan_kernel(const float* __restrict__ slope, const ushort_t* __restrict__ kvT,
                    ushort_t* __restrict__ sT)
{
    const int es = blockIdx.x, bh = blockIdx.y;
    const float s = slope[bh & 15];
    const float bd = __expf(-s * (float)BLOCK_);
    const int tid = threadIdx.x;
    float st[16];
    #pragma unroll
    for (int i = 0; i < 16; ++i) st[i] = 0.f;
    for (int c = 0; c < NC_; ++c) {
        const ushort_t* p = kvT + ((size_t)bh * NC_ + c) * 16384;
        ushort_t* qp = sT + ((size_t)bh * NC_ + c) * 16384;
        #pragma unroll
        for (int i = 0; i < 16; ++i) {
            int lin = tid + i * 256;
            int off = (lin >> 5) * 128 + es * 32 + (lin & 31);
            float x = bf2f(p[off]);
            qp[off] = f2bf(st[i]);
            st[i] = bd * st[i] + x;
        }
    }
}

// ---------------------------------------------------------------------------
// MFMA attention per chunk — unchanged.
// ---------------------------------------------------------------------------
__global__ __launch_bounds__(512)
void attn_mfma(const ushort_t* __restrict__ q, const ushort_t* __restrict__ k,
               const ushort_t* __restrict__ vT, const ushort_t* __restrict__ sT,
               const float* __restrict__ slope, float* __restrict__ o)
{
    const int c = blockIdx.x, bh = blockIdx.y;
    const int h = bh & 15, b = bh >> 4;
    const float s = slope[h];
    const int tid = threadIdx.x, lane = tid & 63, w = tid >> 6;
    const int l15 = lane & 15, l4 = lane >> 4;

    __shared__ __align__(16) ushort_t SH[16384];
    __shared__ __align__(16) ushort_t P[8][2048];

    frag_ab aq[2][4];
    #pragma unroll
    for (int mf = 0; mf < 2; ++mf)
        #pragma unroll
        for (int ks = 0; ks < 4; ++ks) {
            int row = c * BLOCK_ + w * 32 + mf * 16 + l15;
            aq[mf][ks] = *reinterpret_cast<const frag_ab*>(
                q + ((size_t)bh * S_ + row) * HD_ + ks * 32 + l4 * 8);
        }

    frag_cd oa[2][8];
    #pragma unroll
    for (int mf = 0; mf < 2; ++mf)
        #pragma unroll
        for (int ef = 0; ef < 8; ++ef) oa[mf][ef] = 0.f;

    const int wrow = w * 32;
    for (int nt = 0; nt < 4; ++nt) {
        __syncthreads();
        #pragma unroll
        for (int i = 0; i < 2; ++i) {
            int u = tid + i * 512;
            int n = u >> 4, slot = u & 15;
            frag_ab k8 = *reinterpret_cast<const frag_ab*>(
                k + ((size_t)bh * S_ + c * BLOCK_ + nt * 64 + n) * HD_ + slot * 8);
            *reinterpret_cast<frag_ab*>((char*)SH + n * 256 + ((slot * 16) ^ ((n & 7) << 4))) = k8;
        }
        #pragma unroll
        for (int i = 0; i < 2; ++i) {
            int u = tid + i * 512;
            int e = u >> 3, slot = u & 7;
            frag_ab v8 = *reinterpret_cast<const frag_ab*>(
                vT + ((size_t)bh * HD_ + e) * S_ + c * BLOCK_ + nt * 64 + slot * 8);
            *reinterpret_cast<frag_ab*>((char*)SH + 16384 + e * 128 + ((slot * 16) ^ ((e & 7) << 4))) = v8;
        }
        __syncthreads();
        if (nt * 64 > wrow + 31) continue;

        frag_cd pacc[2][4];
        #pragma unroll
        for (int mf = 0; mf < 2; ++mf)
            #pragma unroll
            for (int nf = 0; nf < 4; ++nf) pacc[mf][nf] = 0.f;
        #pragma unroll
        for (int ks = 0; ks < 4; ++ks)
            #pragma unroll
            for (int nf = 0; nf < 4; ++nf) {
                frag_ab bk = *reinterpret_cast<const frag_ab*>(
                    (char*)SH + (nf * 16 + l15) * 256 + ((ks * 64 + l4 * 16) ^ ((l15 & 7) << 4)));
                pacc[0][nf] = __builtin_amdgcn_mfma_f32_16x16x32_bf16(aq[0][ks], bk, pacc[0][nf], 0, 0, 0);
                pacc[1][nf] = __builtin_amdgcn_mfma_f32_16x16x32_bf16(aq[1][ks], bk, pacc[1][nf], 0, 0, 0);
            }
        #pragma unroll
        for (int mf = 0; mf < 2; ++mf)
            #pragma unroll
            for (int nf = 0; nf < 4; ++nf)
                #pragma unroll
                for (int r = 0; r < 4; ++r) {
                    int m = mf * 16 + l4 * 4 + r;
                    int mrow = wrow + m;
                    int ncol = nt * 64 + nf * 16 + l15;
                    float pv = 0.f;
                    if (mrow >= ncol) pv = pacc[mf][nf][r] * __expf(s * (float)(ncol - mrow));
                    *reinterpret_cast<ushort_t*>(
                        (char*)&P[w][0] + m * 128 + (((nf * 16 + l15) * 2) ^ ((m & 7) << 4))) = f2bf(pv);
                }
        __builtin_amdgcn_sched_barrier(0);
        #pragma unroll
        for (int ks = 0; ks < 2; ++ks) {
            frag_ab ap[2];
            #pragma unroll
            for (int mf = 0; mf < 2; ++mf)
                ap[mf] = *reinterpret_cast<const frag_ab*>(
                    (char*)&P[w][0] + (mf * 16 + l15) * 128 + ((ks * 64 + l4 * 16) ^ ((l15 & 7) << 4)));
            #pragma unroll
            for (int ef = 0; ef < 8; ++ef) {
                frag_ab bv = *reinterpret_cast<const frag_ab*>(
                    (char*)SH + 16384 + (ef * 16 + l15) * 128 + ((ks * 64 + l4 * 16) ^ ((l15 & 7) << 4)));
                oa[0][ef] = __builtin_amdgcn_mfma_f32_16x16x32_bf16(ap[0], bv, oa[0][ef], 0, 0, 0);
                oa[1][ef] = __builtin_amdgcn_mfma_f32_16x16x32_bf16(ap[1], bv, oa[1][ef], 0, 0, 0);
            }
        }
    }

    __syncthreads();
    #pragma unroll
    for (int i = 0; i < 4; ++i) {
        int u = tid + i * 512;
        int e = u >> 4, slot = u & 15;
        frag_ab s8 = *reinterpret_cast<const frag_ab*>(
            sT + ((size_t)(bh * NC_ + c)) * 16384 + e * 128 + slot * 8);
        *reinterpret_cast<frag_ab*>((char*)SH + e * 256 + ((slot * 16) ^ ((e & 7) << 4))) = s8;
    }
    __syncthreads();
    #pragma unroll
    for (int mf = 0; mf < 2; ++mf) {
        float qd = __expf(-s * (float)(wrow + mf * 16 + l15 + 1));
        #pragma unroll
        for (int ks = 0; ks < 4; ++ks) {
            frag_ab v = aq[mf][ks];
            #pragma unroll
            for (int j = 0; j < 8; ++j)
                v[j] = (short)f2bf(bf2f((ushort_t)v[j]) * qd);
            aq[mf][ks] = v;
        }
    }
    #pragma unroll
    for (int ks = 0; ks < 4; ++ks)
        #pragma unroll
        for (int ef = 0; ef < 8; ++ef) {
            frag_ab bs = *reinterpret_cast<const frag_ab*>(
                (char*)SH + (ef * 16 + l15) * 256 + ((ks * 64 + l4 * 16) ^ ((l15 & 7) << 4)));
            oa[0][ef] = __builtin_amdgcn_mfma_f32_16x16x32_bf16(aq[0][ks], bs, oa[0][ef], 0, 0, 0);
            oa[1][ef] = __builtin_amdgcn_mfma_f32_16x16x32_bf16(aq[1][ks], bs, oa[1][ef], 0, 0, 0);
        }
    #pragma unroll
    for (int mf = 0; mf < 2; ++mf)
        #pragma unroll
        for (int ef = 0; ef < 8; ++ef)
            #pragma unroll
            for (int r = 0; r < 4; ++r) {
                int row = c * BLOCK_ + wrow + mf * 16 + l4 * 4 + r;
                int col = h * HD_ + ef * 16 + l15;
                o[((size_t)(b * S_ + row)) * H_ + col] = oa[mf][ef][r];
            }
}

// ---------------------------------------------------------------------------
// RMSNorm * norm_weight * gate — unchanged.
// ---------------------------------------------------------------------------
__global__ __launch_bounds__(256)
void norm_gate_kernel(const float* __restrict__ o, const ushort_t* __restrict__ gate,
                      const float* __restrict__ nw, ushort_t* __restrict__ on)
{
    const int row = blockIdx.x;
    const int tid = threadIdx.x;
    const float* orow = o + (size_t)row * H_;
    const ushort_t* grow = gate + (size_t)row * H_;
    ushort_t* onrow = on + (size_t)row * H_;
    float vals[8];
    float ss = 0.f;
    #pragma unroll
    for (int i = 0; i < 8; ++i) {
        vals[i] = orow[tid + i * 256];
        ss += vals[i] * vals[i];
    }
    __shared__ float red[256];
    red[tid] = ss;
    __syncthreads();
    #pragma unroll
    for (int st = 128; st > 0; st >>= 1) {
        if (tid < st) red[tid] += red[tid + st];
        __syncthreads();
    }
    float scale = rsqrtf(red[0] * (1.f / (float)H_) + EPS_);
    #pragma unroll
    for (int i = 0; i < 8; ++i) {
        int cidx = tid + i * 256;
        onrow[cidx] = f2bf(vals[i] * scale * nw[cidx] * bf2f(grow[cidx]));
    }
}

// ---------------------------------------------------------------------------
extern "C" void kernel_launch(void* const* d_in, const int* in_sizes, int n_in,
                              void* d_out, int out_size, void* d_ws, size_t ws_size,
                              hipStream_t stream)
{
    const float* hidden = (const float*)d_in[0];
    const float* mask   = (const float*)d_in[1];
    const float* slope  = (const float*)d_in[2];
    const float* w_qkv  = (const float*)d_in[3];
    const float* w_gate = (const float*)d_in[4];
    const float* w_out  = (const float*)d_in[5];
    const float* nw     = (const float*)d_in[6];

    const size_t MH = (size_t)M_ * H_;                 // 16,777,216 elements
    ushort_t* hid_bf  = (ushort_t*)d_ws;
    ushort_t* on_ws   = hid_bf;
    // r1: wqkvT (6144x2048) + wgateT (2048x2048) contiguous = BT[8192][2048]
    ushort_t* wqkvT   = hid_bf + MH;
    ushort_t* wgateT  = wqkvT + (size_t)6144 * 2048;
    ushort_t* kvT_ws  = wqkvT;
    ushort_t* sT_ws   = wqkvT + MH / 2;
    ushort_t* woutT   = wqkvT;
    ushort_t* q_ws    = hid_bf + 2 * MH;
    ushort_t* k_ws    = q_ws + MH;
    ushort_t* vT_ws   = k_ws + MH;
    ushort_t* gate_ws = vT_ws + MH;
    ushort_t* kT_ws   = (ushort_t*)d_out;
    float*    o_f32   = (float*)d_out;

    dim3 blk(256);
    cast_bf16_kernel<<<(MH / 4) / 256, blk, 0, stream>>>(hidden, hid_bf);
    transpose_cast_kernel<<<dim3(6144 / 32, 2048 / 32), blk, 0, stream>>>(w_qkv, wqkvT, 2048, 6144);
    transpose_cast_kernel<<<dim3(2048 / 32, 2048 / 32), blk, 0, stream>>>(w_gate, wgateT, 2048, 2048);
    // 1+2. combined qkv+gate GEMM (N=8192), round-8 exact schedule
    gemm256<2><<<dim3((M_ / 256) * (8192 / 256)), dim3(512), 0, stream>>>(
        hid_bf, wqkvT, M_, 8192, 2048,
        nullptr, q_ws, k_ws, kT_ws, vT_ws, gate_ws, mask);
    // 3. per-chunk KV^T contributions
    kv_chunk_mfma<<<dim3(NC_, B_ * NH_), blk, 0, stream>>>(kT_ws, vT_ws, slope, kvT_ws);
    // 4. prefix scan -> S^T per chunk
    kv_scan_kernel<<<dim3(4, B_ * NH_), blk, 0, stream>>>(slope, kvT_ws, sT_ws);
    // 5. attention -> o f32 into d_out
    attn_mfma<<<dim3(NC_, B_ * NH_), dim3(512), 0, stream>>>(
        q_ws, k_ws, vT_ws, sT_ws, slope, o_f32);
    // prep final weight (kvT dead; sT untouched)
    transpose_cast_kernel<<<dim3(2048 / 32, 2048 / 32), blk, 0, stream>>>(w_out, woutT, 2048, 2048);
    // 6. RMSNorm * nw * gate -> bf16 o_n
    norm_gate_kernel<<<M_, blk, 0, stream>>>(o_f32, gate_ws, nw, on_ws);
    // 7. out = o_n @ w_out (round-8 exact schedule, f32 C)
    gemm256<0><<<dim3((M_ / 256) * (2048 / 256)), dim3(512), 0, stream>>>(
        on_ws, woutT, M_, 2048, 2048,
        (float*)d_out, nullptr, nullptr, nullptr, nullptr, nullptr, nullptr);
}